// Round 6
// baseline (142.561 us; speedup 1.0000x reference)
//
#include <hip/hip_runtime.h>
#include <hip/hip_bf16.h>

#define LOG2E 1.4426950408889634f
#define LN2   0.6931471805599453f

typedef __attribute__((ext_vector_type(8))) short bf16x8;
typedef __attribute__((ext_vector_type(4))) float f32x4;

static __device__ __forceinline__ short f2bf(float f) {
  __hip_bfloat16 h = __float2bfloat16(f);
  return *reinterpret_cast<short*>(&h);
}

static __device__ __forceinline__ void gll16(const float* gsrc, float* ldst) {
  // per-lane global src; LDS dest = wave-uniform base + lane*16B
  __builtin_amdgcn_global_load_lds(
      (const __attribute__((address_space(1))) void*)gsrc,
      (__attribute__((address_space(3))) void*)ldst, 16, 0, 0);
}

// ---------------------------------------------------------------------------
// wprep: pack W (f32 [256][64]) into per-lane MFMA B-fragments (bf16).
// wfrag[enc][f][lane][j], f=nsub*8+ks; elem = W[ks*32+(lane>>4)*8+j][nsub*16+(lane&15)]
// ---------------------------------------------------------------------------
__global__ __launch_bounds__(256) void wprep_kernel(
    const float* __restrict__ Ww, const float* __restrict__ Wi,
    ushort* __restrict__ wfrag)
{
  int id = blockIdx.x * 256 + threadIdx.x;       // 0..4095
  if (id >= 4096) return;
  int enc  = id >> 11;
  int f    = (id >> 6) & 31;
  int l    = id & 63;
  int nsub = f >> 3, ks = f & 7;
  const float* __restrict__ W = enc ? Wi : Ww;
  int n  = nsub * 16 + (l & 15);
  int k0 = ks * 32 + (l >> 4) * 8;
  ushort* dst = wfrag + ((size_t)(enc * 32 + f) * 64 + l) * 8;
#pragma unroll
  for (int j = 0; j < 8; ++j)
    dst[j] = (ushort)f2bf(W[(size_t)(k0 + j) * 64 + n]);
}

// ---------------------------------------------------------------------------
// enc_mfma6: 3-buffer LDS pipeline, compiler-opaque LDS reads.
// Block = 4 waves; LDS = 3 x 16KB x-tiles only (48KB -> 3 blocks/CU).
// Stage via global_load_lds; ds_read via INLINE ASM so the compiler cannot
// insert vmcnt(0) drains (that was R3-R5's hidden serializer). Counted
// vmcnt(16) keeps strips k+1..k+3 in flight across barriers. W B-frags are
// strip-invariant in VGPRs (keep-alive pinned). Requires M%16==0.
// ---------------------------------------------------------------------------
__global__ __launch_bounds__(256, 3) void enc_mfma6_kernel(
    const float* __restrict__ x0, const float* __restrict__ b0,
    const float* __restrict__ x1, const float* __restrict__ b1,
    const ushort* __restrict__ wfrag, float* __restrict__ out, int M)
{
  __shared__ float xtile[3][4096];                // 48 KB

  const int enc = blockIdx.y;
  const float* __restrict__ x   = enc ? x1 : x0;
  const float* __restrict__ bia = enc ? b1 : b0;
  float* __restrict__ o = out + (size_t)enc * (size_t)M * 64u;

  const int lane = threadIdx.x & 63;
  const int wid  = threadIdx.x >> 6;
  const int rsel = lane & 15;                     // A row / C col within tile
  const int kgrp = lane >> 4;                     // k-group / C row-group
  const int sw   = rsel & 7;

  const int nstrips = M >> 4;                     // M % 16 == 0
  const int bx = blockIdx.x, G = gridDim.x;
  const int niter = (bx < nstrips) ? ((nstrips - 1 - bx) / G + 1) : 0;
  if (niter == 0) return;

  // strip-invariant W fragments + bias: pinned so they can't turn into
  // in-loop VMEM ops (which would corrupt the vmcnt accounting).
  bf16x8 wf[8];
#pragma unroll
  for (int ks = 0; ks < 8; ++ks) {
    wf[ks] = *(const bf16x8*)(wfrag +
        ((size_t)((enc * 32 + wid * 8 + ks) * 64 + lane)) * 8);
    asm volatile("" : "+v"(wf[ks]));
  }
  float bv = bia[wid * 16 + rsel];
  asm volatile("" : "+v"(bv));

  // wave stages its 4 rows of strip s into buffer `buf` (4 glls, 1KB each)
  auto stage = [&](int s, int buf) {
#pragma unroll
    for (int j = 0; j < 4; ++j) {
      int R = wid * 4 + j;
      const float* gs = x + (size_t)(s * 16 + R) * 256u + ((lane ^ (R & 7)) << 2);
      gll16(gs, &xtile[buf][R * 256]);
    }
  };

  // prologue: fill 3 buffers (indices clamped for short niter)
  stage(bx, 0);
  stage(bx + ((1 < niter) ? 1 : (niter - 1)) * G, 1);
  stage(bx + ((2 < niter) ? 2 : (niter - 1)) * G, 2);
  __builtin_amdgcn_sched_barrier(0);

  for (int k = 0; k < niter; ++k) {
    // counted wait: strip k's 4 glls retired. Ops issued after them:
    // k=0: G1,G2 (8); k=1: G2,S0,G3 (12); k>=2: S(k-2),G(k+1),S(k-1),G(k+2) (16)
    if (k == 0)      asm volatile("s_waitcnt vmcnt(8)" ::: "memory");
    else if (k == 1) asm volatile("s_waitcnt vmcnt(12)" ::: "memory");
    else             asm volatile("s_waitcnt vmcnt(16)" ::: "memory");
    __builtin_amdgcn_sched_barrier(0);
    __builtin_amdgcn_s_barrier();                 // tile k fully staged
    __builtin_amdgcn_sched_barrier(0);

    const int b = k % 3;
    unsigned base = (unsigned)(unsigned long)
        (__attribute__((address_space(3))) char*)&xtile[b][0];
    unsigned rowb = base + (unsigned)(rsel << 10);

    // compiler-opaque LDS reads (16 x ds_read_b128)
    f32x4 rv[16];
#pragma unroll
    for (int ks = 0; ks < 8; ++ks) {
      int c0 = ks * 8 + kgrp * 2;
      unsigned a0 = rowb + (unsigned)(((c0)     ^ sw) << 4);
      unsigned a1 = rowb + (unsigned)(((c0 + 1) ^ sw) << 4);
      asm volatile("ds_read_b128 %0, %1" : "=&v"(rv[2 * ks])     : "v"(a0));
      asm volatile("ds_read_b128 %0, %1" : "=&v"(rv[2 * ks + 1]) : "v"(a1));
    }
    asm volatile("s_waitcnt lgkmcnt(0)" ::: "memory");
    __builtin_amdgcn_sched_barrier(0);            // rule #18: fence hoisting
    __builtin_amdgcn_s_barrier();                 // all waves done with buf b
    __builtin_amdgcn_sched_barrier(0);

    // restage freed buffer with strip k+3 (clamped -> uniform VM op count)
    int sn = k + 3; if (sn >= niter) sn = niter - 1;
    stage(bx + sn * G, b);
    __builtin_amdgcn_sched_barrier(0);

    // convert to bf16 A-fragments
    bf16x8 a[8];
#pragma unroll
    for (int ks = 0; ks < 8; ++ks) {
      f32x4 lo = rv[2 * ks], hi = rv[2 * ks + 1];
      a[ks][0] = f2bf(lo.x); a[ks][1] = f2bf(lo.y);
      a[ks][2] = f2bf(lo.z); a[ks][3] = f2bf(lo.w);
      a[ks][4] = f2bf(hi.x); a[ks][5] = f2bf(hi.y);
      a[ks][6] = f2bf(hi.z); a[ks][7] = f2bf(hi.w);
    }

    // MFMA: this wave's 16-col slice (nsub = wid)
    f32x4 acc = f32x4{0.f, 0.f, 0.f, 0.f};
#pragma unroll
    for (int ks = 0; ks < 8; ++ks)
      acc = __builtin_amdgcn_mfma_f32_16x16x32_bf16(a[ks], wf[ks], acc, 0, 0, 0);

    // epilogue: bias + leaky relu; C/D: col=lane&15, row=kgrp*4+r
    const int s = bx + k * G;
    const int crow = s * 16 + kgrp * 4;
    float* orow = o + (size_t)crow * 64u + wid * 16 + rsel;
#pragma unroll
    for (int r = 0; r < 4; ++r) {
      float v = acc[r] + bv;
      v = fmaxf(v, 0.01f * v);
      orow[r * 64] = v;                           // 4 dword stores, countable
    }
    __builtin_amdgcn_sched_barrier(0);
  }
}

// ---------------------------------------------------------------------------
// Kernel B: pw = xw @ W_edge[0:64,:] (+b) ; pi = xi @ W_edge[64:128,:]
// rows padded to 16 floats (single-128B-line gathers); b_edge folded in.
// ---------------------------------------------------------------------------
__global__ __launch_bounds__(256) void proj_kernel(
    const float* __restrict__ feats, const float* __restrict__ W_edge,
    const float* __restrict__ b_edge, float* __restrict__ ws, int M)
{
  const int enc = blockIdx.y;
  int row = blockIdx.x * 256 + threadIdx.x;
  if (row >= M) return;
  const float4* __restrict__ f4 =
      (const float4*)(feats + ((size_t)enc * M + row) * 64u);
  const float* __restrict__ W2 = W_edge + enc * 640;   // 64 rows x 10 cols

  float acc[10];
#pragma unroll
  for (int k = 0; k < 10; ++k) acc[k] = enc ? 0.f : b_edge[k];

#pragma unroll 4
  for (int n4 = 0; n4 < 16; ++n4) {
    float4 xv = f4[n4];
    const float* w = W2 + n4 * 40;
#pragma unroll
    for (int k = 0; k < 10; ++k) acc[k] = fmaf(xv.x, w[k],      acc[k]);
#pragma unroll
    for (int k = 0; k < 10; ++k) acc[k] = fmaf(xv.y, w[10 + k], acc[k]);
#pragma unroll
    for (int k = 0; k < 10; ++k) acc[k] = fmaf(xv.z, w[20 + k], acc[k]);
#pragma unroll
    for (int k = 0; k < 10; ++k) acc[k] = fmaf(xv.w, w[30 + k], acc[k]);
  }

  float* orow = ws + ((size_t)enc * M + row) * 16u;
#pragma unroll
  for (int k = 0; k < 10; ++k) orow[k] = acc[k];
}

// ---------------------------------------------------------------------------
// Kernel C: logits[e] = pw[e0] + pi[e1]; log_softmax; dense float4 stores.
// ---------------------------------------------------------------------------
__global__ __launch_bounds__(256) void edge_kernel(
    const int* __restrict__ ei, const float* __restrict__ ws,
    float* __restrict__ out, int E, int M)
{
  __shared__ float sm[2560];
  long e = (long)blockIdx.x * 256 + threadIdx.x;
  float l[10];
#pragma unroll
  for (int k = 0; k < 10; ++k) l[k] = 0.f;

  if (e < E) {
    int e0 = ei[e];
    int e1 = ei[E + e];
    const float4* pw = (const float4*)ws + (size_t)e0 * 4u;
    const float4* pi = (const float4*)ws + ((size_t)M + e1) * 4u;
    float4 a0 = pw[0], a1 = pw[1], a2 = pw[2];
    float4 c0 = pi[0], c1 = pi[1], c2 = pi[2];
    l[0] = a0.x + c0.x; l[1] = a0.y + c0.y; l[2] = a0.z + c0.z; l[3] = a0.w + c0.w;
    l[4] = a1.x + c1.x; l[5] = a1.y + c1.y; l[6] = a1.z + c1.z; l[7] = a1.w + c1.w;
    l[8] = a2.x + c2.x; l[9] = a2.y + c2.y;
    float m = l[0];
#pragma unroll
    for (int k = 1; k < 10; ++k) m = fmaxf(m, l[k]);
    float s = 0.f;
#pragma unroll
    for (int k = 0; k < 10; ++k) { l[k] = (l[k] - m) * LOG2E; s += exp2f(l[k]); }
    float ls = log2f(s);
#pragma unroll
    for (int k = 0; k < 10; ++k) l[k] = (l[k] - ls) * LN2;
  }

#pragma unroll
  for (int k = 0; k < 10; ++k) sm[threadIdx.x * 10 + k] = l[k];
  __syncthreads();
  const f32x4* sm4 = (const f32x4*)sm;
  f32x4* ob = (f32x4*)(out + (size_t)blockIdx.x * 2560u);
  long lim4 = ((long)E * 10) >> 2;
  long base4 = (long)blockIdx.x * 640;
#pragma unroll
  for (int j = 0; j < 3; ++j) {
    int idx = j * 256 + threadIdx.x;
    if (idx < 640 && base4 + idx < lim4) ob[idx] = sm4[idx];
  }
}

// ---------------------------------------------------------------------------
// Fallbacks (only if d_ws too small or M%16 != 0).
// ---------------------------------------------------------------------------
__global__ __launch_bounds__(256) void enc_kernel_f32(
    const float* __restrict__ x0, const float* __restrict__ W0, const float* __restrict__ b0,
    const float* __restrict__ x1, const float* __restrict__ W1, const float* __restrict__ b1,
    float* __restrict__ out, int M)
{
  const int enc = blockIdx.y;
  const float* __restrict__ x = enc ? x1 : x0;
  const float* __restrict__ W = enc ? W1 : W0;
  const float* __restrict__ b = enc ? b1 : b0;
  float* __restrict__ o = out + (size_t)enc * (size_t)M * 64u;

  const int lane = threadIdx.x & 63;
  const int wid  = threadIdx.x >> 6;
  int row0 = __builtin_amdgcn_readfirstlane(blockIdx.x * 64 + wid * 16);
  const float* __restrict__ xrow = x + (size_t)row0 * 256u;

  float acc[16];
#pragma unroll
  for (int r = 0; r < 16; ++r) acc[r] = 0.f;

  if (row0 + 16 <= M) {
#pragma unroll 4
    for (int k = 0; k < 256; ++k) {
      float wv = W[k * 64 + lane];
#pragma unroll
      for (int r = 0; r < 16; ++r)
        acc[r] = fmaf(xrow[r * 256 + k], wv, acc[r]);
    }
    float bias = b[lane];
#pragma unroll
    for (int r = 0; r < 16; ++r) {
      float v = acc[r] + bias;
      v = fmaxf(v, 0.01f * v);
      o[(size_t)(row0 + r) * 64u + lane] = v;
    }
  } else if (row0 < M) {
    int nr = M - row0;
    for (int k = 0; k < 256; ++k) {
      float wv = W[k * 64 + lane];
      for (int r = 0; r < nr; ++r)
        acc[r] = fmaf(xrow[r * 256 + k], wv, acc[r]);
    }
    float bias = b[lane];
    for (int r = 0; r < nr; ++r) {
      float v = acc[r] + bias;
      v = fmaxf(v, 0.01f * v);
      o[(size_t)(row0 + r) * 64u + lane] = v;
    }
  }
}

__global__ __launch_bounds__(256) void edge_kernel_direct(
    const int* __restrict__ ei, const float* __restrict__ feats,
    const float* __restrict__ W_edge, const float* __restrict__ b_edge,
    float* __restrict__ out, int E, int M)
{
  __shared__ float sm[2560];
  long e = (long)blockIdx.x * 256 + threadIdx.x;
  float l[10];
#pragma unroll
  for (int k = 0; k < 10; ++k) l[k] = 0.f;

  if (e < E) {
    int e0 = ei[e];
    int e1 = ei[E + e];
#pragma unroll
    for (int k = 0; k < 10; ++k) l[k] = b_edge[k];
    const float4* fw = (const float4*)(feats + (size_t)e0 * 64u);
    const float4* fi = (const float4*)(feats + ((size_t)M + e1) * 64u);
#pragma unroll 4
    for (int n4 = 0; n4 < 16; ++n4) {
      float4 xv = fw[n4];
      const float* w = W_edge + n4 * 40;
#pragma unroll
      for (int k = 0; k < 10; ++k) l[k] = fmaf(xv.x, w[k],      l[k]);
#pragma unroll
      for (int k = 0; k < 10; ++k) l[k] = fmaf(xv.y, w[10 + k], l[k]);
#pragma unroll
      for (int k = 0; k < 10; ++k) l[k] = fmaf(xv.z, w[20 + k], l[k]);
#pragma unroll
      for (int k = 0; k < 10; ++k) l[k] = fmaf(xv.w, w[30 + k], l[k]);
    }
#pragma unroll 4
    for (int n4 = 0; n4 < 16; ++n4) {
      float4 xv = fi[n4];
      const float* w = W_edge + 640 + n4 * 40;
#pragma unroll
      for (int k = 0; k < 10; ++k) l[k] = fmaf(xv.x, w[k],      l[k]);
#pragma unroll
      for (int k = 0; k < 10; ++k) l[k] = fmaf(xv.y, w[10 + k], l[k]);
#pragma unroll
      for (int k = 0; k < 10; ++k) l[k] = fmaf(xv.z, w[20 + k], l[k]);
#pragma unroll
      for (int k = 0; k < 10; ++k) l[k] = fmaf(xv.w, w[30 + k], l[k]);
    }
    float m = l[0];
#pragma unroll
    for (int k = 1; k < 10; ++k) m = fmaxf(m, l[k]);
    float s = 0.f;
#pragma unroll
    for (int k = 0; k < 10; ++k) { l[k] = (l[k] - m) * LOG2E; s += exp2f(l[k]); }
    float ls = log2f(s);
#pragma unroll
    for (int k = 0; k < 10; ++k) l[k] = (l[k] - ls) * LN2;
  }

#pragma unroll
  for (int k = 0; k < 10; ++k) sm[threadIdx.x * 10 + k] = l[k];
  __syncthreads();
  const f32x4* sm4 = (const f32x4*)sm;
  f32x4* ob = (f32x4*)(out + (size_t)blockIdx.x * 2560u);
  long lim4 = ((long)E * 10) >> 2;
  long base4 = (long)blockIdx.x * 640;
#pragma unroll
  for (int j = 0; j < 3; ++j) {
    int idx = j * 256 + threadIdx.x;
    if (idx < 640 && base4 + idx < lim4) ob[idx] = sm4[idx];
  }
}

extern "C" void kernel_launch(void* const* d_in, const int* in_sizes, int n_in,
                              void* d_out, int out_size, void* d_ws, size_t ws_size,
                              hipStream_t stream)
{
  const float* x_w = (const float*)d_in[0];
  const float* x_i = (const float*)d_in[1];
  const int*   ei  = (const int*)d_in[2];
  const float* W_w = (const float*)d_in[3];
  const float* b_w = (const float*)d_in[4];
  const float* W_i = (const float*)d_in[5];
  const float* b_i = (const float*)d_in[6];
  const float* W_e = (const float*)d_in[7];
  const float* b_e = (const float*)d_in[8];
  float* out = (float*)d_out;

  const int M = in_sizes[0] / 256;   // 100000
  const int E = in_sizes[2] / 2;     // 2000000

  float* logout = out + (size_t)2 * (size_t)M * 64u;

  const size_t pw_bytes = (size_t)2 * (size_t)M * 16u * sizeof(float);
  const size_t ws_need  = pw_bytes + 65536;     // + wfrag table

  if (ws_size >= ws_need && (M % 16) == 0) {
    float*  ws    = (float*)d_ws;
    ushort* wfrag = (ushort*)((char*)d_ws + pw_bytes);

    wprep_kernel<<<16, 256, 0, stream>>>(W_w, W_i, wfrag);

    dim3 gA(384, 2);                 // 768 blocks = 3/CU (48KB LDS each)
    enc_mfma6_kernel<<<gA, 256, 0, stream>>>(x_w, b_w, x_i, b_i, wfrag, out, M);

    dim3 gB((M + 255) / 256, 2);
    proj_kernel<<<gB, 256, 0, stream>>>(out, W_e, b_e, ws, M);

    dim3 gC((unsigned)((E + 255) / 256));
    edge_kernel<<<gC, 256, 0, stream>>>(ei, ws, logout, E, M);
  } else {
    dim3 gA0((M + 63) / 64, 2);
    enc_kernel_f32<<<gA0, 256, 0, stream>>>(x_w, W_w, b_w, x_i, W_i, b_i, out, M);
    dim3 gC((unsigned)((E + 255) / 256));
    edge_kernel_direct<<<gC, 256, 0, stream>>>(ei, out, W_e, b_e, logout, E, M);
  }
}